// Round 11
// baseline (502.984 us; speedup 1.0000x reference)
//
#include <hip/hip_runtime.h>
#include <hip/hip_bf16.h>

// VQ-VAE vector quantizer, MI355X (gfx950).
//   inputs : z (8,256,16,16,16) fp32, codebook (1024,256) fp32
//   output : quant (8,256,16,16,16) ++ idx (8,16,16,16) ++ loss (1), fp32 flat
//
// Round 11: SINGLE-pass MFMA scan with per-lane top-2 + index tracking
// (R10's pass 2 re-issued all B-loads/MFMAs just to regenerate scores).
//   Per (group,row) each lane sees 16 codes (code nn of its 16 tiles); track
//   min1/idx1/min2 in registers (5 VALU/elem, no cross-lane, no atomics).
//   Completeness: argmin k* has A(k*)<Amin+M; either it is its lane's min1
//   (appended: min1<thr) or min2<=A(k*)<thr -> lane overflow appends its 16
//   codes incl. k*. Candidate set is a fixed predicate -> deterministic.
//   Appends run ONCE post-scan (ballot machinery verified R8-R10).
//   Recheck: verified exact np-fp32 pipeline D = fl(fl(Sz+Se)-2*dot),
//   dot = ascending-d fp32 FMA chain, Sz/Se numpy pairwise order, lex-min
//   (D,k) == np.argmin first occurrence; overflow(>CAP) -> exact full scan.
//   Loss fused via device-scope done-counter (verified R8-R10).

#define K_CODES 1024
#define DIM 256
#define N_TOK 32768
#define SPATIAL 4096
#define TOK_BLK 32
#define CAP 32
#define MARGIN 1e-3f
#define ZPITCH 257

typedef __attribute__((ext_vector_type(8))) short short8;
typedef __attribute__((ext_vector_type(4))) float float4v;

// ws layout in floats
#define WS_LOSS 0
#define WS_DONE_I 1   // int slot: completed-block counter
#define WS_E2 16      // 1024 floats: Se[k] (np pairwise)
#define WS_EB 2048    // 262144 bf16: codebook, B-fragment order

#define O_IDX (8 * DIM * SPATIAL)  // 8388608
#define O_LOSS (O_IDX + N_TOK)     // 8421376
#define N_BLOCKS (N_TOK / TOK_BLK) // 1024

__device__ __forceinline__ short f2bf(float v) {  // RTNE fp32->bf16 bits
  unsigned u = __float_as_uint(v);
  u = (u + 0x7fffu + ((u >> 16) & 1u)) >> 16;
  return (short)u;
}

// prep (verified R8-R10): coalesced fragment pack + Se (np pairwise).
// Fragment layout: element (code k, dim d): T=k>>4, nn=k&15, f=d>>5,
// q=(d>>3)&3, j=d&7 -> short off ((T*8+f)*64 + (q*16+nn))*8 + j.
__global__ __launch_bounds__(256) void prep_kernel(const float* __restrict__ e,
                                                   float* __restrict__ ws) {
  int T = blockIdx.x, tid = threadIdx.x;
#pragma unroll
  for (int ii = 0; ii < 2; ii++) {
    int idx = ii * 256 + tid;  // 512 short8 fragments per 16-code tile
    int f = idx >> 6, lane = idx & 63;
    int q = lane >> 4, nn = lane & 15;
    const float* src = e + (size_t)(T * 16 + nn) * DIM + f * 32 + q * 8;
    float4 lo = *(const float4*)src;
    float4 hi = *(const float4*)(src + 4);
    unsigned s0 = (unsigned short)f2bf(lo.x) | ((unsigned)(unsigned short)f2bf(lo.y) << 16);
    unsigned s1 = (unsigned short)f2bf(lo.z) | ((unsigned)(unsigned short)f2bf(lo.w) << 16);
    unsigned s2 = (unsigned short)f2bf(hi.x) | ((unsigned)(unsigned short)f2bf(hi.y) << 16);
    unsigned s3 = (unsigned short)f2bf(hi.z) | ((unsigned)(unsigned short)f2bf(hi.w) << 16);
    uint4 p = {s0, s1, s2, s3};
    ((uint4*)(ws + WS_EB))[(T * 8 + f) * 64 + lane] = p;  // coalesced 16B
  }
  if (tid < 128) {  // Se: 8 slots per code, np pairwise (verified)
    int c8 = tid >> 3, slot = tid & 7;
    int k = T * 16 + c8;
    const float* er = e + (size_t)k * DIM;
    float res01[2];
#pragma unroll
    for (int blk = 0; blk < 2; blk++) {
      float v0 = er[blk * 128 + slot];
      float rj = __fmul_rn(v0, v0);
      for (int i = 1; i < 16; i++) {
        float v = er[blk * 128 + i * 8 + slot];
        rj = __fadd_rn(rj, __fmul_rn(v, v));
      }
      float a = __fadd_rn(rj, __shfl_down(rj, 1, 8));
      float bq = __fadd_rn(a, __shfl_down(a, 2, 8));
      res01[blk] = __fadd_rn(bq, __shfl_down(bq, 4, 8));  // valid on slot 0
    }
    if (slot == 0) ws[WS_E2 + k] = __fadd_rn(res01[0], res01[1]);
  }
  if (T == 0 && tid == 0) {
    ws[WS_LOSS] = 0.f;
    ((int*)ws)[WS_DONE_I] = 0;
  }
}

__global__ __launch_bounds__(256, 2) void main_kernel(const float* __restrict__ z,
                                                      const float* __restrict__ e,
                                                      float* __restrict__ ws,
                                                      float* __restrict__ out) {
  __shared__ float zl[TOK_BLK * ZPITCH];  // 32.9 KB: z-tile [tok][d]
  __shared__ unsigned short cand[TOK_BLK][CAP];
  __shared__ int cnt[TOK_BLK];
  __shared__ float wsmin[4][TOK_BLK];
  __shared__ float thrS[TOK_BLK];
  __shared__ int mini_sh[TOK_BLK];
  __shared__ float red[4];

  int tid = threadIdx.x, w = tid >> 6, lane = tid & 63;
  int quad = lane >> 4, nn = lane & 15;
  int n0 = blockIdx.x * TOK_BLK;
  int b = n0 >> 12, s0 = n0 & 4095;
  const float* zb = z + (size_t)b * DIM * SPATIAL + s0;
  const float* Se = ws + WS_E2;

  if (tid < TOK_BLK) cnt[tid] = 0;

  // ---- stage z-tile once: float4 global loads -> zl[t][d] ----
#pragma unroll
  for (int i = 0; i < 8; i++) {
    int idx = i * 256 + tid;  // 2048 float4 groups: d = idx>>3, g = idx&7
    int d = idx >> 3, g = idx & 7;
    float4 v = *(const float4*)(zb + (size_t)d * SPATIAL + g * 4);
    zl[(4 * g + 0) * ZPITCH + d] = v.x;
    zl[(4 * g + 1) * ZPITCH + d] = v.y;
    zl[(4 * g + 2) * ZPITCH + d] = v.z;
    zl[(4 * g + 3) * ZPITCH + d] = v.w;
  }
  __syncthreads();  // zl ready; cnt=0 visible

  // ---- A fragments (z -> bf16) from LDS, 2 groups of 16 tokens ----
  short8 A0[8], A1[8];
#pragma unroll
  for (int f = 0; f < 8; f++) {
    short8 a0, a1;
#pragma unroll
    for (int j = 0; j < 8; j++) {
      int d = f * 32 + quad * 8 + j;
      a0[j] = f2bf(zl[nn * ZPITCH + d]);
      a1[j] = f2bf(zl[(16 + nn) * ZPITCH + d]);
    }
    A0[f] = a0;
    A1[f] = a1;
  }

  const short8* eB8 = (const short8*)(ws + WS_EB);

  // ---- SINGLE pass: MFMA scan + per-lane top-2/idx (wave w: w*256..+255) ----
  float mn1[2][4], mn2[2][4];
  int ix1[2][4];
#pragma unroll
  for (int g = 0; g < 2; g++)
#pragma unroll
    for (int r = 0; r < 4; r++) {
      mn1[g][r] = 3.4e38f;
      mn2[g][r] = 3.4e38f;
      ix1[g][r] = w * 256 + nn;
    }
  for (int c = 0; c < 16; c++) {
    int T = w * 16 + c;  // k = T*16 + nn
    float4v C0 = {0.f, 0.f, 0.f, 0.f}, C1 = {0.f, 0.f, 0.f, 0.f};
#pragma unroll
    for (int f = 0; f < 8; f++) {
      short8 Bf = eB8[(size_t)(T * 8 + f) * 64 + lane];  // L2-resident
      C0 = __builtin_amdgcn_mfma_f32_16x16x32_bf16(A0[f], Bf, C0, 0, 0, 0);
      C1 = __builtin_amdgcn_mfma_f32_16x16x32_bf16(A1[f], Bf, C1, 0, 0, 0);
    }
    float SeK = Se[T * 16 + nn];
    int k = T * 16 + nn;
#pragma unroll
    for (int r = 0; r < 4; r++) {
      float s0 = fmaf(-2.f, C0[r], SeK);
      mn2[0][r] = fminf(mn2[0][r], fmaxf(mn1[0][r], s0));  // 2nd-min (pre-update)
      ix1[0][r] = (s0 < mn1[0][r]) ? k : ix1[0][r];
      mn1[0][r] = fminf(mn1[0][r], s0);
      float s1 = fmaf(-2.f, C1[r], SeK);
      mn2[1][r] = fminf(mn2[1][r], fmaxf(mn1[1][r], s1));
      ix1[1][r] = (s1 < mn1[1][r]) ? k : ix1[1][r];
      mn1[1][r] = fminf(mn1[1][r], s1);
    }
  }
  // cross-lane per-token quarter min of mn1 -> wsmin
#pragma unroll
  for (int r = 0; r < 4; r++) {
    float m0 = mn1[0][r], m1 = mn1[1][r];
    m0 = fminf(m0, __shfl_xor(m0, 1, 16));
    m0 = fminf(m0, __shfl_xor(m0, 2, 16));
    m0 = fminf(m0, __shfl_xor(m0, 4, 16));
    m0 = fminf(m0, __shfl_xor(m0, 8, 16));
    m1 = fminf(m1, __shfl_xor(m1, 1, 16));
    m1 = fminf(m1, __shfl_xor(m1, 2, 16));
    m1 = fminf(m1, __shfl_xor(m1, 4, 16));
    m1 = fminf(m1, __shfl_xor(m1, 8, 16));
    if (nn == 0) {
      wsmin[w][quad * 4 + r] = m0;
      wsmin[w][16 + quad * 4 + r] = m1;
    }
  }
  __syncthreads();
  if (tid < TOK_BLK)
    thrS[tid] = fminf(fminf(wsmin[0][tid], wsmin[1][tid]),
                      fminf(wsmin[2][tid], wsmin[3][tid])) + MARGIN;
  __syncthreads();

  // ---- one-shot candidate append (runs once, not per tile) ----
#pragma unroll
  for (int g = 0; g < 2; g++) {
#pragma unroll
    for (int r = 0; r < 4; r++) {
      int t = g * 16 + quad * 4 + r;
      float thr = thrS[t];
      bool p1 = mn1[g][r] < thr;
      unsigned long long bl = __ballot(p1);
      unsigned grp = (unsigned)((bl >> (quad * 16)) & 0xffffULL);
      if (grp) {
        int base = 0;
        if (nn == 0) base = atomicAdd(&cnt[t], __popc(grp));
        base = __shfl(base, quad * 16, 64);
        if (p1) {
          int pos = base + __popc(grp & ((1u << nn) - 1u));
          if (pos < CAP) cand[t][pos] = (unsigned short)ix1[g][r];
        }
      }
      if (mn2[g][r] < thr) {  // rare: >=2 below-thr in this lane's 16 codes
        int base2 = atomicAdd(&cnt[t], 16);
#pragma unroll
        for (int c2 = 0; c2 < 16; c2++) {
          int pos = base2 + c2;
          if (pos < CAP) cand[t][pos] = (unsigned short)((w * 16 + c2) * 16 + nn);
        }
      }
    }
  }
  __syncthreads();

  // ---- Recheck: 32 tokens x 8 slots; exact np-fp32 pipeline (verified) ----
  {
    int t = tid >> 3, slot = tid & 7;
    const float* zt = zl + t * ZPITCH;
    float res01[2];  // Sz in exact numpy pairwise shape, slot-parallel
#pragma unroll
    for (int blk = 0; blk < 2; blk++) {
      float v0 = zt[blk * 128 + slot];
      float rj = __fmul_rn(v0, v0);
      for (int i = 1; i < 16; i++) {
        float v = zt[blk * 128 + i * 8 + slot];
        rj = __fadd_rn(rj, __fmul_rn(v, v));
      }
      float a = __fadd_rn(rj, __shfl_down(rj, 1, 8));
      float bq = __fadd_rn(a, __shfl_down(a, 2, 8));
      res01[blk] = __fadd_rn(bq, __shfl_down(bq, 4, 8));
    }
    float Szn = __fadd_rn(res01[0], res01[1]);
    Szn = __shfl(Szn, lane & ~7, 64);  // broadcast slot0

    int cc = cnt[t];
    float bD = 3.4e38f;
    int bK = 0x7fffffff;
    if (cc <= CAP) {
      for (int c = slot; c < cc; c += 8) {
        int k = cand[t][c];
        const float* er = e + (size_t)k * DIM;
        float acc = 0.f;
        for (int d = 0; d < DIM; d++) acc = fmaf(zt[d], er[d], acc);
        float D = __fsub_rn(__fadd_rn(Szn, Se[k]), __fmul_rn(2.f, acc));
        if (D < bD || (D == bD && k < bK)) { bD = D; bK = k; }
      }
    } else {  // overflow: exact full scan (rare, deterministic)
      for (int k = slot; k < K_CODES; k += 8) {
        const float* er = e + (size_t)k * DIM;
        float acc = 0.f;
        for (int d = 0; d < DIM; d++) acc = fmaf(zt[d], er[d], acc);
        float D = __fsub_rn(__fadd_rn(Szn, Se[k]), __fmul_rn(2.f, acc));
        if (D < bD || (D == bD && k < bK)) { bD = D; bK = k; }
      }
    }
#pragma unroll
    for (int off = 4; off > 0; off >>= 1) {  // lex-min across 8 slots
      float oD = __shfl_down(bD, off, 8);
      int oK = __shfl_down(bK, off, 8);
      if (oD < bD || (oD == bD && oK < bK)) { bD = oD; bK = oK; }
    }
    if (slot == 0) {
      mini_sh[t] = bK;
      out[O_IDX + n0 + t] = (float)bK;
    }
  }
  __syncthreads();

  // ---- Epilogue: quant store (e rows from L2) + fused loss ----
  float sumsq = 0.f;
  float* op = out + (size_t)b * DIM * SPATIAL + s0;
  for (int i = 0; i < 32; i++) {
    int idx = i * 256 + tid;  // 8192 elements
    int d = idx >> 5, t2 = idx & 31;
    float v = e[(size_t)mini_sh[t2] * DIM + d];
    float zv = zl[t2 * ZPITCH + d];
    float df = __fsub_rn(v, zv);
    sumsq = fmaf(df, df, sumsq);
    op[(size_t)d * SPATIAL + t2] = v;  // 128 B contiguous per 32 lanes
  }
#pragma unroll
  for (int o = 32; o > 0; o >>= 1) sumsq += __shfl_down(sumsq, o, 64);
  if (lane == 0) red[w] = sumsq;
  __syncthreads();
  if (tid == 0) {
    atomicAdd(ws + WS_LOSS, red[0] + red[1] + red[2] + red[3]);
    __threadfence();  // loss add visible before counter bump
    int done = atomicAdd((int*)ws + WS_DONE_I, 1);
    if (done == N_BLOCKS - 1) {  // last block: all adds complete & visible
      __threadfence();
      float total = atomicAdd(ws + WS_LOSS, 0.f);  // read via atomic path
      out[O_LOSS] = 1.25f * total / 8388608.f;
    }
  }
}

extern "C" void kernel_launch(void* const* d_in, const int* in_sizes, int n_in,
                              void* d_out, int out_size, void* d_ws, size_t ws_size,
                              hipStream_t stream) {
  const float* z = (const float*)d_in[0];
  const float* e = (const float*)d_in[1];
  float* ws = (float*)d_ws;
  float* out = (float*)d_out;

  prep_kernel<<<K_CODES / 16, 256, 0, stream>>>(e, ws);
  main_kernel<<<N_BLOCKS, 256, 0, stream>>>(z, e, ws, out);
}